// Round 1
// baseline (2852.392 us; speedup 1.0000x reference)
//
#include <hip/hip_runtime.h>
#include <cstdint>
#include <cstddef>

#define N_NODES 100000
#define N_EDGES 3200000
#define N_FEAT  512
#define HIDDEN  16

// ---------------------------------------------------------------------------
// async global -> LDS, 16B per lane. LDS dest is wave-uniform base + lane*16.
__device__ __forceinline__ void gload_lds16(const float* g, void* lds) {
  __builtin_amdgcn_global_load_lds(
      (const __attribute__((address_space(1))) void*)g,
      (__attribute__((address_space(3))) void*)lds, 16, 0, 0);
}

// ---------------------------------------------------------------------------
// Kernel 1: xw[r][c] = sum_k x[r][k] * W1[k][c]     (N_FEAT=512, 16 outputs)
// 1-wave blocks, lane = row, 64 rows/block. K staged in 32-float chunks,
// double-buffered, counted vmcnt(8), no barriers. XOR-swizzled LDS layout:
// slot (row, q') holds x[row][ 4*(q' ^ (row&7)) .. +3 ]  (inverse swizzle
// applied on the global source address; LDS writes stay linear).
__global__ __launch_bounds__(64)
void k_gemm1(const float* __restrict__ x, const float* __restrict__ W1,
             float* __restrict__ xw) {
  __shared__ float4 xs[2][512];          // 2 x 8KB
  const int l = threadIdx.x;             // 0..63, lane == local row
  const int rbase = blockIdx.x * 64;

  float acc[16];
#pragma unroll
  for (int c = 0; c < 16; ++c) acc[c] = 0.f;

  const int srow = l >> 3;               // row-sub within an 8-row group
  const int sq   = l & 7;                // destination quad slot
  const int kq   = sq ^ srow;            // source quad (inverse swizzle); row&7 == srow

  auto STAGE = [&](int b, int ck) {
    const int kb = ck * 32;
#pragma unroll
    for (int i = 0; i < 8; ++i) {
      int grow = rbase + i * 8 + srow;
      if (grow >= N_NODES) grow = N_NODES - 1;   // clamp: keep instr count fixed
      gload_lds16(x + (size_t)grow * N_FEAT + kb + kq * 4, &xs[b][i * 64]);
    }
  };

  auto COMPUTE = [&](int b, int ck) {
    const int kb = ck * 32;
#pragma unroll
    for (int q = 0; q < 8; ++q) {
      float4 xv = xs[b][l * 8 + (q ^ (l & 7))];  // conflict-free after swizzle
      float xe[4] = {xv.x, xv.y, xv.z, xv.w};
#pragma unroll
      for (int j = 0; j < 4; ++j) {
        const float* wrow = W1 + (size_t)(kb + q * 4 + j) * 16;  // wave-uniform -> s_load
#pragma unroll
        for (int c = 0; c < 16; ++c)
          acc[c] = fmaf(xe[j], wrow[c], acc[c]);
      }
    }
  };

  STAGE(0, 0);
#pragma unroll 1
  for (int ck = 0; ck < 16; ++ck) {
    const int b = ck & 1;
    if (ck + 1 < 16) {
      STAGE(b ^ 1, ck + 1);
      asm volatile("s_waitcnt vmcnt(8)" ::: "memory");   // 8 oldest (this buf) done
    } else {
      asm volatile("s_waitcnt vmcnt(0)" ::: "memory");
    }
    COMPUTE(b, ck);
  }

  const int grow = rbase + l;
  if (grow < N_NODES) {
    float4* o = (float4*)(xw + (size_t)grow * 16);
    o[0] = make_float4(acc[0],  acc[1],  acc[2],  acc[3]);
    o[1] = make_float4(acc[4],  acc[5],  acc[6],  acc[7]);
    o[2] = make_float4(acc[8],  acc[9],  acc[10], acc[11]);
    o[3] = make_float4(acc[12], acc[13], acc[14], acc[15]);
  }
}

// ---------------------------------------------------------------------------
// Kernel 2: hacc[rows[e]][c] += vals[e] * xw[cols[e]][c]   (16 f32 atomics/edge)
__global__ __launch_bounds__(256)
void k_spmm1(const float* __restrict__ vals, const int* __restrict__ rows,
             const int* __restrict__ cols, const float* __restrict__ xw,
             float* __restrict__ hacc) {
  const int e = blockIdx.x * 256 + threadIdx.x;
  if (e >= N_EDGES) return;
  const float v = vals[e];
  const int r = rows[e], c = cols[e];
  const float4* s = (const float4*)(xw + (size_t)c * 16);
  float4 a0 = s[0], a1 = s[1], a2 = s[2], a3 = s[3];
  float* h = hacc + (size_t)r * 16;
  atomicAdd(h + 0,  v * a0.x);  atomicAdd(h + 1,  v * a0.y);
  atomicAdd(h + 2,  v * a0.z);  atomicAdd(h + 3,  v * a0.w);
  atomicAdd(h + 4,  v * a1.x);  atomicAdd(h + 5,  v * a1.y);
  atomicAdd(h + 6,  v * a1.z);  atomicAdd(h + 7,  v * a1.w);
  atomicAdd(h + 8,  v * a2.x);  atomicAdd(h + 9,  v * a2.y);
  atomicAdd(h + 10, v * a2.z);  atomicAdd(h + 11, v * a2.w);
  atomicAdd(h + 12, v * a3.x);  atomicAdd(h + 13, v * a3.y);
  atomicAdd(h + 14, v * a3.z);  atomicAdd(h + 15, v * a3.w);
}

// ---------------------------------------------------------------------------
// Kernel 3: hw1[r] = sum_c relu(hacc[r][c] + b1[c]) * W2[c]
__global__ __launch_bounds__(256)
void k_layer2(const float* __restrict__ hacc, const float* __restrict__ b1,
              const float* __restrict__ W2, float* __restrict__ hw1) {
  const int r = blockIdx.x * 256 + threadIdx.x;
  if (r >= N_NODES) return;
  const float4* hp = (const float4*)(hacc + (size_t)r * 16);
  float s = 0.f;
#pragma unroll
  for (int i = 0; i < 4; ++i) {
    float4 h4 = hp[i];
    float hv[4] = {h4.x, h4.y, h4.z, h4.w};
#pragma unroll
    for (int j = 0; j < 4; ++j) {
      const int c = i * 4 + j;
      float h = fmaxf(hv[j] + b1[c], 0.f);
      s = fmaf(h, W2[c], s);
    }
  }
  hw1[r] = s;
}

// ---------------------------------------------------------------------------
// Kernel 4: oacc[rows[e]] += vals[e] * hw1[cols[e]]
__global__ __launch_bounds__(256)
void k_spmm2(const float* __restrict__ vals, const int* __restrict__ rows,
             const int* __restrict__ cols, const float* __restrict__ hw1,
             float* __restrict__ oacc) {
  const int e = blockIdx.x * 256 + threadIdx.x;
  if (e >= N_EDGES) return;
  atomicAdd(oacc + rows[e], vals[e] * hw1[cols[e]]);
}

// ---------------------------------------------------------------------------
// Kernel 5: out[r] = sigmoid(oacc[r] + b2)
__global__ __launch_bounds__(256)
void k_final(const float* __restrict__ oacc, const float* __restrict__ b2,
             float* __restrict__ out) {
  const int r = blockIdx.x * 256 + threadIdx.x;
  if (r >= N_NODES) return;
  const float z = oacc[r] + b2[0];
  out[r] = 1.f / (1.f + expf(-z));
}

// ---------------------------------------------------------------------------
extern "C" void kernel_launch(void* const* d_in, const int* in_sizes, int n_in,
                              void* d_out, int out_size, void* d_ws, size_t ws_size,
                              hipStream_t stream) {
  const float* x    = (const float*)d_in[0];
  const float* vals = (const float*)d_in[1];
  const float* W1   = (const float*)d_in[2];
  const float* b1   = (const float*)d_in[3];
  const float* W2   = (const float*)d_in[4];
  const float* b2   = (const float*)d_in[5];
  const int*   rows = (const int*)d_in[6];
  const int*   cols = (const int*)d_in[7];
  float* out = (float*)d_out;

  // workspace layout (floats): xw[N*16] | hacc[N*16] | oacc[N] | hw1[N]
  float* xw   = (float*)d_ws;
  float* hacc = xw   + (size_t)N_NODES * 16;
  float* oacc = hacc + (size_t)N_NODES * 16;
  float* hw1  = oacc + (size_t)N_NODES;

  // zero the two accumulators (contiguous: hacc then oacc)
  hipMemsetAsync(hacc, 0, ((size_t)N_NODES * 16 + N_NODES) * sizeof(float), stream);

  k_gemm1 <<<(N_NODES + 63) / 64,    64,  0, stream>>>(x, W1, xw);
  k_spmm1 <<<(N_EDGES + 255) / 256,  256, 0, stream>>>(vals, rows, cols, xw, hacc);
  k_layer2<<<(N_NODES + 255) / 256,  256, 0, stream>>>(hacc, b1, W2, hw1);
  k_spmm2 <<<(N_EDGES + 255) / 256,  256, 0, stream>>>(vals, rows, cols, hw1, oacc);
  k_final <<<(N_NODES + 255) / 256,  256, 0, stream>>>(oacc, b2, out);
}

// Round 2
// 516.437 us; speedup vs baseline: 5.5232x; 5.5232x over previous
//
#include <hip/hip_runtime.h>
#include <cstdint>
#include <cstddef>

#define N_NODES 100000
#define N_EDGES 3200000
#define N_FEAT  512
#define HIDDEN  16
#define SCAN_T  1024

// ---------------------------------------------------------------------------
// async global -> LDS, 16B per lane. LDS dest is wave-uniform base + lane*16.
__device__ __forceinline__ void gload_lds16(const float* g, void* lds) {
  __builtin_amdgcn_global_load_lds(
      (const __attribute__((address_space(1))) void*)g,
      (__attribute__((address_space(3))) void*)lds, 16, 0, 0);
}

// ---------------------------------------------------------------------------
// Kernel 1: xw[r][c] = sum_k x[r][k] * W1[k][c]     (N_FEAT=512, 16 outputs)
// 1-wave blocks, lane = row, 64 rows/block, double-buffered global_load_lds
// with counted vmcnt(8); XOR-swizzled LDS (inverse swizzle on global source).
__global__ __launch_bounds__(64)
void k_gemm1(const float* __restrict__ x, const float* __restrict__ W1,
             float* __restrict__ xw) {
  __shared__ float4 xs[2][512];          // 2 x 8KB
  const int l = threadIdx.x;
  const int rbase = blockIdx.x * 64;

  float acc[16];
#pragma unroll
  for (int c = 0; c < 16; ++c) acc[c] = 0.f;

  const int srow = l >> 3;
  const int sq   = l & 7;
  const int kq   = sq ^ srow;            // inverse swizzle on source

  auto STAGE = [&](int b, int ck) {
    const int kb = ck * 32;
#pragma unroll
    for (int i = 0; i < 8; ++i) {
      int grow = rbase + i * 8 + srow;
      if (grow >= N_NODES) grow = N_NODES - 1;
      gload_lds16(x + (size_t)grow * N_FEAT + kb + kq * 4, &xs[b][i * 64]);
    }
  };

  auto COMPUTE = [&](int b, int ck) {
    const int kb = ck * 32;
#pragma unroll
    for (int q = 0; q < 8; ++q) {
      float4 xv = xs[b][l * 8 + (q ^ (l & 7))];
      float xe[4] = {xv.x, xv.y, xv.z, xv.w};
#pragma unroll
      for (int j = 0; j < 4; ++j) {
        const float* wrow = W1 + (size_t)(kb + q * 4 + j) * 16;
#pragma unroll
        for (int c = 0; c < 16; ++c)
          acc[c] = fmaf(xe[j], wrow[c], acc[c]);
      }
    }
  };

  STAGE(0, 0);
#pragma unroll 1
  for (int ck = 0; ck < 16; ++ck) {
    const int b = ck & 1;
    if (ck + 1 < 16) {
      STAGE(b ^ 1, ck + 1);
      asm volatile("s_waitcnt vmcnt(8)" ::: "memory");
    } else {
      asm volatile("s_waitcnt vmcnt(0)" ::: "memory");
    }
    COMPUTE(b, ck);
  }

  const int grow = rbase + l;
  if (grow < N_NODES) {
    float4* o = (float4*)(xw + (size_t)grow * 16);
    o[0] = make_float4(acc[0],  acc[1],  acc[2],  acc[3]);
    o[1] = make_float4(acc[4],  acc[5],  acc[6],  acc[7]);
    o[2] = make_float4(acc[8],  acc[9],  acc[10], acc[11]);
    o[3] = make_float4(acc[12], acc[13], acc[14], acc[15]);
  }
}

// ---------------------------------------------------------------------------
// CSR build, pass 1: per-row counts + per-edge rank (only 3.2M int atomics).
__global__ __launch_bounds__(256)
void k_hist(const int* __restrict__ rows, int* __restrict__ counts,
            unsigned short* __restrict__ pos) {
  const int e = blockIdx.x * 256 + threadIdx.x;
  if (e >= N_EDGES) return;
  const int p = atomicAdd(&counts[rows[e]], 1);
  pos[e] = (unsigned short)p;            // max row degree << 65536
}

// ---------------------------------------------------------------------------
// CSR build, pass 2: single-workgroup exclusive scan of counts -> row_start.
__global__ __launch_bounds__(SCAN_T)
void k_scan(const int* __restrict__ counts, int* __restrict__ row_start) {
  __shared__ int sums[SCAN_T];
  const int t = threadIdx.x;
  const int per = (N_NODES + SCAN_T - 1) / SCAN_T;   // 98
  const int base = t * per;
  const int lim = base + per < N_NODES ? base + per : N_NODES;
  int s = 0;
  for (int i = base; i < lim; ++i) s += counts[i];
  sums[t] = s;
  __syncthreads();
  for (int off = 1; off < SCAN_T; off <<= 1) {       // inclusive Hillis-Steele
    int add = (t >= off) ? sums[t - off] : 0;
    __syncthreads();
    sums[t] += add;
    __syncthreads();
  }
  int run = sums[t] - s;                             // exclusive prefix
  for (int i = base; i < lim; ++i) { row_start[i] = run; run += counts[i]; }
  if (t == SCAN_T - 1) row_start[N_NODES] = N_EDGES;
}

// ---------------------------------------------------------------------------
// CSR build, pass 3: atomic-free scatter into packed (col, val) list.
__global__ __launch_bounds__(256)
void k_scatter(const int* __restrict__ rows, const int* __restrict__ cols,
               const float* __restrict__ vals, const int* __restrict__ row_start,
               const unsigned short* __restrict__ pos, int2* __restrict__ epack) {
  const int e = blockIdx.x * 256 + threadIdx.x;
  if (e >= N_EDGES) return;
  const int dst = row_start[rows[e]] + (int)pos[e];
  epack[dst] = make_int2(cols[e], __float_as_int(vals[e]));
}

// ---------------------------------------------------------------------------
// Fused layer-1 tail: gather-SPMM + bias + relu + (.) @ W2 -> hw1[r].
// 16 lanes per row (lane = hidden channel), 16 rows per 256-thread block.
__global__ __launch_bounds__(256)
void k_fused1(const int2* __restrict__ epack, const int* __restrict__ row_start,
              const float* __restrict__ xw, const float* __restrict__ b1,
              const float* __restrict__ W2, float* __restrict__ hw1) {
  const int t = threadIdx.x;
  const int lane16 = t & 15;
  const int r = blockIdx.x * 16 + (t >> 4);
  if (r >= N_NODES) return;
  const int s = row_start[r], e = row_start[r + 1];
  float a0 = 0.f, a1 = 0.f;
  int i = s;
  for (; i + 1 < e; i += 2) {                        // 2x unroll for MLP
    int2 ea = epack[i], eb = epack[i + 1];
    a0 = fmaf(__int_as_float(ea.y), xw[(size_t)ea.x * 16 + lane16], a0);
    a1 = fmaf(__int_as_float(eb.y), xw[(size_t)eb.x * 16 + lane16], a1);
  }
  if (i < e) {
    int2 ea = epack[i];
    a0 = fmaf(__int_as_float(ea.y), xw[(size_t)ea.x * 16 + lane16], a0);
  }
  float h = fmaxf(a0 + a1 + b1[lane16], 0.f);
  float p = h * W2[lane16];
#pragma unroll
  for (int m = 8; m >= 1; m >>= 1) p += __shfl_xor(p, m, 16);
  if (lane16 == 0) hw1[r] = p;
}

// ---------------------------------------------------------------------------
// Fused layer-2 tail: gather-SPMM on scalars + bias + sigmoid -> out[r].
__global__ __launch_bounds__(256)
void k_fused2(const int2* __restrict__ epack, const int* __restrict__ row_start,
              const float* __restrict__ hw1, const float* __restrict__ b2,
              float* __restrict__ out) {
  const int t = threadIdx.x;
  const int lane16 = t & 15;
  const int r = blockIdx.x * 16 + (t >> 4);
  if (r >= N_NODES) return;
  const int s = row_start[r], e = row_start[r + 1];
  float acc = 0.f;
  for (int i = s + lane16; i < e; i += 16) {
    int2 ev = epack[i];
    acc = fmaf(__int_as_float(ev.y), hw1[ev.x], acc);
  }
#pragma unroll
  for (int m = 8; m >= 1; m >>= 1) acc += __shfl_xor(acc, m, 16);
  if (lane16 == 0) out[r] = 1.f / (1.f + expf(-(acc + b2[0])));
}

// ---------------------------------------------------------------------------
extern "C" void kernel_launch(void* const* d_in, const int* in_sizes, int n_in,
                              void* d_out, int out_size, void* d_ws, size_t ws_size,
                              hipStream_t stream) {
  const float* x    = (const float*)d_in[0];
  const float* vals = (const float*)d_in[1];
  const float* W1   = (const float*)d_in[2];
  const float* b1   = (const float*)d_in[3];
  const float* W2   = (const float*)d_in[4];
  const float* b2   = (const float*)d_in[5];
  const int*   rows = (const int*)d_in[6];
  const int*   cols = (const int*)d_in[7];
  float* out = (float*)d_out;

  // workspace layout (16B-aligned chunks):
  // xw[N*16]f | epack[E]int2 | pos[E]u16 | counts[N]i | row_start[N+1]i | hw1[N]f
  char* w = (char*)d_ws;
  float*          xw        = (float*)w;              w += (size_t)N_NODES * 16 * 4;
  int2*           epack     = (int2*)w;               w += (size_t)N_EDGES * 8;
  unsigned short* pos       = (unsigned short*)w;     w += (size_t)N_EDGES * 2;
  int*            counts    = (int*)w;                w += (size_t)N_NODES * 4;
  int*            row_start = (int*)w;                w += (size_t)(N_NODES + 4) * 4;
  float*          hw1       = (float*)w;

  hipMemsetAsync(counts, 0, (size_t)N_NODES * 4, stream);

  k_gemm1  <<<(N_NODES + 63) / 64,   64,     0, stream>>>(x, W1, xw);
  k_hist   <<<(N_EDGES + 255) / 256, 256,    0, stream>>>(rows, counts, pos);
  k_scan   <<<1,                     SCAN_T, 0, stream>>>(counts, row_start);
  k_scatter<<<(N_EDGES + 255) / 256, 256,    0, stream>>>(rows, cols, vals,
                                                          row_start, pos, epack);
  k_fused1 <<<(N_NODES + 15) / 16,   256,    0, stream>>>(epack, row_start, xw,
                                                          b1, W2, hw1);
  k_fused2 <<<(N_NODES + 15) / 16,   256,    0, stream>>>(epack, row_start, hw1,
                                                          b2, out);
}

// Round 3
// 355.907 us; speedup vs baseline: 8.0144x; 1.4510x over previous
//
#include <hip/hip_runtime.h>
#include <cstdint>
#include <cstddef>

#define N_NODES 100000
#define N_EDGES 3200000
#define N_FEAT  512
#define HIDDEN  16
#define NB_SCAN ((N_NODES + 255) / 256)   // 391

// ---------------------------------------------------------------------------
// async global -> LDS, 16B per lane. LDS dest is wave-uniform base + lane*16.
__device__ __forceinline__ void gload_lds16(const float* g, void* lds) {
  __builtin_amdgcn_global_load_lds(
      (const __attribute__((address_space(1))) void*)g,
      (__attribute__((address_space(3))) void*)lds, 16, 0, 0);
}

// ---------------------------------------------------------------------------
// Kernel 1: xw[r][c] = sum_k x[r][k] * W1[k][c]     (N_FEAT=512, 16 outputs)
// 1-wave blocks, lane = row, 64 rows/block, double-buffered global_load_lds
// with counted vmcnt(8); XOR-swizzled LDS (inverse swizzle on global source).
__global__ __launch_bounds__(64)
void k_gemm1(const float* __restrict__ x, const float* __restrict__ W1,
             float* __restrict__ xw) {
  __shared__ float4 xs[2][512];          // 2 x 8KB
  const int l = threadIdx.x;
  const int rbase = blockIdx.x * 64;

  float acc[16];
#pragma unroll
  for (int c = 0; c < 16; ++c) acc[c] = 0.f;

  const int srow = l >> 3;
  const int sq   = l & 7;
  const int kq   = sq ^ srow;            // inverse swizzle on source

  auto STAGE = [&](int b, int ck) {
    const int kb = ck * 32;
#pragma unroll
    for (int i = 0; i < 8; ++i) {
      int grow = rbase + i * 8 + srow;
      if (grow >= N_NODES) grow = N_NODES - 1;
      gload_lds16(x + (size_t)grow * N_FEAT + kb + kq * 4, &xs[b][i * 64]);
    }
  };

  auto COMPUTE = [&](int b, int ck) {
    const int kb = ck * 32;
#pragma unroll
    for (int q = 0; q < 8; ++q) {
      float4 xv = xs[b][l * 8 + (q ^ (l & 7))];
      float xe[4] = {xv.x, xv.y, xv.z, xv.w};
#pragma unroll
      for (int j = 0; j < 4; ++j) {
        const float* wrow = W1 + (size_t)(kb + q * 4 + j) * 16;
#pragma unroll
        for (int c = 0; c < 16; ++c)
          acc[c] = fmaf(xe[j], wrow[c], acc[c]);
      }
    }
  };

  STAGE(0, 0);
#pragma unroll 1
  for (int ck = 0; ck < 16; ++ck) {
    const int b = ck & 1;
    if (ck + 1 < 16) {
      STAGE(b ^ 1, ck + 1);
      asm volatile("s_waitcnt vmcnt(8)" ::: "memory");
    } else {
      asm volatile("s_waitcnt vmcnt(0)" ::: "memory");
    }
    COMPUTE(b, ck);
  }

  const int grow = rbase + l;
  if (grow < N_NODES) {
    float4* o = (float4*)(xw + (size_t)grow * 16);
    o[0] = make_float4(acc[0],  acc[1],  acc[2],  acc[3]);
    o[1] = make_float4(acc[4],  acc[5],  acc[6],  acc[7]);
    o[2] = make_float4(acc[8],  acc[9],  acc[10], acc[11]);
    o[3] = make_float4(acc[12], acc[13], acc[14], acc[15]);
  }
}

// ---------------------------------------------------------------------------
// CSR build, pass 1: per-row counts + per-edge rank (only 3.2M int atomics).
__global__ __launch_bounds__(256)
void k_hist(const int* __restrict__ rows, int* __restrict__ counts,
            unsigned short* __restrict__ pos) {
  const int e = blockIdx.x * 256 + threadIdx.x;
  if (e >= N_EDGES) return;
  const int p = atomicAdd(&counts[rows[e]], 1);
  pos[e] = (unsigned short)p;            // max row degree << 65536
}

// ---------------------------------------------------------------------------
// Device-wide exclusive scan of counts -> row_start, 3 phases.
// Phase 1: per-block (256 counts) sums -> partials[NB_SCAN].
__global__ __launch_bounds__(256)
void k_scan1(const int* __restrict__ counts, int* __restrict__ partials) {
  __shared__ int wsum[4];
  const int t = threadIdx.x;
  const int i = blockIdx.x * 256 + t;
  int v = (i < N_NODES) ? counts[i] : 0;
#pragma unroll
  for (int m = 32; m >= 1; m >>= 1) v += __shfl_down(v, m, 64);
  if ((t & 63) == 0) wsum[t >> 6] = v;
  __syncthreads();
  if (t == 0) partials[blockIdx.x] = wsum[0] + wsum[1] + wsum[2] + wsum[3];
}

// Phase 2: single block, exclusive scan of NB_SCAN partials -> blk_off.
__global__ __launch_bounds__(512)
void k_scan2(const int* __restrict__ partials, int* __restrict__ blk_off) {
  __shared__ int s[512];
  const int t = threadIdx.x;
  int v = (t < NB_SCAN) ? partials[t] : 0;
  s[t] = v;
  __syncthreads();
#pragma unroll
  for (int off = 1; off < 512; off <<= 1) {
    int add = (t >= off) ? s[t - off] : 0;
    __syncthreads();
    s[t] += add;
    __syncthreads();
  }
  if (t < NB_SCAN) blk_off[t] = s[t] - v;            // exclusive
}

// Phase 3: in-block exclusive scan + block offset -> row_start.
__global__ __launch_bounds__(256)
void k_scan3(const int* __restrict__ counts, const int* __restrict__ blk_off,
             int* __restrict__ row_start) {
  __shared__ int s[256];
  const int t = threadIdx.x;
  const int i = blockIdx.x * 256 + t;
  int v = (i < N_NODES) ? counts[i] : 0;
  s[t] = v;
  __syncthreads();
#pragma unroll
  for (int off = 1; off < 256; off <<= 1) {
    int add = (t >= off) ? s[t - off] : 0;
    __syncthreads();
    s[t] += add;
    __syncthreads();
  }
  if (i < N_NODES) row_start[i] = blk_off[blockIdx.x] + s[t] - v;
  if (i == N_NODES - 1) row_start[N_NODES] = N_EDGES;
}

// ---------------------------------------------------------------------------
// CSR build, pass 3: atomic-free scatter into packed (col, val) list.
__global__ __launch_bounds__(256)
void k_scatter(const int* __restrict__ rows, const int* __restrict__ cols,
               const float* __restrict__ vals, const int* __restrict__ row_start,
               const unsigned short* __restrict__ pos, int2* __restrict__ epack) {
  const int e = blockIdx.x * 256 + threadIdx.x;
  if (e >= N_EDGES) return;
  const int dst = row_start[rows[e]] + (int)pos[e];
  epack[dst] = make_int2(cols[e], __float_as_int(vals[e]));
}

// ---------------------------------------------------------------------------
// Fused layer-1 tail: gather-SPMM + bias + relu + (.) @ W2 -> hw1[r].
// 16 lanes per row (lane = hidden channel), 16 rows per 256-thread block.
__global__ __launch_bounds__(256)
void k_fused1(const int2* __restrict__ epack, const int* __restrict__ row_start,
              const float* __restrict__ xw, const float* __restrict__ b1,
              const float* __restrict__ W2, float* __restrict__ hw1) {
  const int t = threadIdx.x;
  const int lane16 = t & 15;
  const int r = blockIdx.x * 16 + (t >> 4);
  if (r >= N_NODES) return;
  const int s = row_start[r], e = row_start[r + 1];
  float a0 = 0.f, a1 = 0.f;
  int i = s;
  for (; i + 1 < e; i += 2) {                        // 2x unroll for MLP
    int2 ea = epack[i], eb = epack[i + 1];
    a0 = fmaf(__int_as_float(ea.y), xw[(size_t)ea.x * 16 + lane16], a0);
    a1 = fmaf(__int_as_float(eb.y), xw[(size_t)eb.x * 16 + lane16], a1);
  }
  if (i < e) {
    int2 ea = epack[i];
    a0 = fmaf(__int_as_float(ea.y), xw[(size_t)ea.x * 16 + lane16], a0);
  }
  float h = fmaxf(a0 + a1 + b1[lane16], 0.f);
  float p = h * W2[lane16];
#pragma unroll
  for (int m = 8; m >= 1; m >>= 1) p += __shfl_xor(p, m, 16);
  if (lane16 == 0) hw1[r] = p;
}

// ---------------------------------------------------------------------------
// Fused layer-2 tail: gather-SPMM on scalars + bias + sigmoid -> out[r].
__global__ __launch_bounds__(256)
void k_fused2(const int2* __restrict__ epack, const int* __restrict__ row_start,
              const float* __restrict__ hw1, const float* __restrict__ b2,
              float* __restrict__ out) {
  const int t = threadIdx.x;
  const int lane16 = t & 15;
  const int r = blockIdx.x * 16 + (t >> 4);
  if (r >= N_NODES) return;
  const int s = row_start[r], e = row_start[r + 1];
  float acc = 0.f;
  for (int i = s + lane16; i < e; i += 16) {
    int2 ev = epack[i];
    acc = fmaf(__int_as_float(ev.y), hw1[ev.x], acc);
  }
#pragma unroll
  for (int m = 8; m >= 1; m >>= 1) acc += __shfl_xor(acc, m, 16);
  if (lane16 == 0) out[r] = 1.f / (1.f + expf(-(acc + b2[0])));
}

// ---------------------------------------------------------------------------
extern "C" void kernel_launch(void* const* d_in, const int* in_sizes, int n_in,
                              void* d_out, int out_size, void* d_ws, size_t ws_size,
                              hipStream_t stream) {
  const float* x    = (const float*)d_in[0];
  const float* vals = (const float*)d_in[1];
  const float* W1   = (const float*)d_in[2];
  const float* b1   = (const float*)d_in[3];
  const float* W2   = (const float*)d_in[4];
  const float* b2   = (const float*)d_in[5];
  const int*   rows = (const int*)d_in[6];
  const int*   cols = (const int*)d_in[7];
  float* out = (float*)d_out;

  // workspace layout (16B-aligned chunks):
  // xw[N*16]f | epack[E]int2 | pos[E]u16 | counts[N]i | row_start[N+1]i |
  // hw1[N]f | partials[NB]i | blk_off[NB]i
  char* w = (char*)d_ws;
  float*          xw        = (float*)w;              w += (size_t)N_NODES * 16 * 4;
  int2*           epack     = (int2*)w;               w += (size_t)N_EDGES * 8;
  unsigned short* pos       = (unsigned short*)w;     w += (size_t)N_EDGES * 2;
  int*            counts    = (int*)w;                w += (size_t)N_NODES * 4;
  int*            row_start = (int*)w;                w += (size_t)(N_NODES + 4) * 4;
  float*          hw1       = (float*)w;              w += (size_t)N_NODES * 4;
  int*            partials  = (int*)w;                w += (size_t)((NB_SCAN + 3) & ~3) * 4;
  int*            blk_off   = (int*)w;

  hipMemsetAsync(counts, 0, (size_t)N_NODES * 4, stream);

  k_gemm1  <<<(N_NODES + 63) / 64,   64,  0, stream>>>(x, W1, xw);
  k_hist   <<<(N_EDGES + 255) / 256, 256, 0, stream>>>(rows, counts, pos);
  k_scan1  <<<NB_SCAN,               256, 0, stream>>>(counts, partials);
  k_scan2  <<<1,                     512, 0, stream>>>(partials, blk_off);
  k_scan3  <<<NB_SCAN,               256, 0, stream>>>(counts, blk_off, row_start);
  k_scatter<<<(N_EDGES + 255) / 256, 256, 0, stream>>>(rows, cols, vals,
                                                       row_start, pos, epack);
  k_fused1 <<<(N_NODES + 15) / 16,   256, 0, stream>>>(epack, row_start, xw,
                                                       b1, W2, hw1);
  k_fused2 <<<(N_NODES + 15) / 16,   256, 0, stream>>>(epack, row_start, hw1,
                                                       b2, out);
}